// Round 1
// baseline (244.036 us; speedup 1.0000x reference)
//
#include <hip/hip_runtime.h>

// Problem constants: B=1, T=5, C=64, H=W=32, F=10
#define N_TOK   5120      // T*H*W
#define C_IN    64
#define F_OUT   10
#define FP      12        // padded row stride for q/k/v rows (3 x float4)

#define N_CHUNKS 16       // denom pass: n-split
#define NC_LEN   320      // 5120/16
#define M_CHUNKS 32       // main pass: m-split
#define MC_LEN   160      // 5120/32

// ---------------------------------------------------------------------------
// Kernel A: compute q = W1*x1+b1, k = W2*x2+b2, v = W3*x1+b3  -> [N][FP] rows
// x layout: input[t][c][p], p = h*32+w; n = t*1024+p
// ---------------------------------------------------------------------------
__global__ __launch_bounds__(256) void qkv_kernel(
    const float* __restrict__ x1, const float* __restrict__ x2,
    const float* __restrict__ w1, const float* __restrict__ b1,
    const float* __restrict__ w2, const float* __restrict__ b2,
    const float* __restrict__ w3, const float* __restrict__ b3,
    float* __restrict__ Q, float* __restrict__ K, float* __restrict__ V)
{
    // weights transposed into LDS: s[c][f], f-contiguous for vector broadcast
    __shared__ float s1[C_IN * FP], s2[C_IN * FP], s3[C_IN * FP];
    int tid = threadIdx.x;
    for (int i = tid; i < C_IN * F_OUT; i += 256) {
        int f = i >> 6, c = i & 63;               // i = f*64 + c
        s1[c * FP + f] = w1[i];
        s2[c * FP + f] = w2[i];
        s3[c * FP + f] = w3[i];
    }
    __syncthreads();

    int n = blockIdx.x * 256 + tid;               // 20 blocks * 256 = 5120
    int t = n >> 10, p = n & 1023;
    const float* x1p = x1 + t * (C_IN * 1024) + p;
    const float* x2p = x2 + t * (C_IN * 1024) + p;

    float qa[F_OUT], ka[F_OUT], va[F_OUT];
#pragma unroll
    for (int f = 0; f < F_OUT; ++f) { qa[f] = b1[f]; ka[f] = b2[f]; va[f] = b3[f]; }

    for (int c = 0; c < C_IN; ++c) {
        float a = x1p[c * 1024];
        float b = x2p[c * 1024];
#pragma unroll
        for (int f = 0; f < F_OUT; ++f) {
            qa[f] = fmaf(s1[c * FP + f], a, qa[f]);
            ka[f] = fmaf(s2[c * FP + f], b, ka[f]);
            va[f] = fmaf(s3[c * FP + f], a, va[f]);
        }
    }
#pragma unroll
    for (int f = 0; f < F_OUT; ++f) {
        Q[n * FP + f] = qa[f];
        K[n * FP + f] = ka[f];
        V[n * FP + f] = va[f];
    }
    // zero pads so float4 reads of rows are clean
    Q[n * FP + 10] = 0.f; Q[n * FP + 11] = 0.f;
    K[n * FP + 10] = 0.f; K[n * FP + 11] = 0.f;
    V[n * FP + 10] = 0.f; V[n * FP + 11] = 0.f;
}

// ---------------------------------------------------------------------------
// Kernel B: partial softmax denominators.
// dpart[nc][m] = sum_{n in chunk nc} exp(min(s[n,m],60))
// thread owns column m (k in regs); q[:,n] is wave-uniform per iteration.
// ---------------------------------------------------------------------------
__global__ __launch_bounds__(256) void denom_kernel(
    const float* __restrict__ Q, const float* __restrict__ K,
    float* __restrict__ dpart)
{
    int mTile = blockIdx.x % 20;
    int nc    = blockIdx.x / 20;       // 20*16 = 320 blocks
    int m = mTile * 256 + threadIdx.x;

    float kk[F_OUT];
#pragma unroll
    for (int f = 0; f < F_OUT; ++f) kk[f] = K[m * FP + f];

    float d = 0.f;
    int n0 = nc * NC_LEN;
    for (int n = n0; n < n0 + NC_LEN; ++n) {
        const float4* qp = (const float4*)(Q + n * FP);
        float4 qa = qp[0], qb = qp[1], qc = qp[2];
        float qq[12] = {qa.x, qa.y, qa.z, qa.w, qb.x, qb.y, qb.z, qb.w,
                        qc.x, qc.y, qc.z, qc.w};
        float s = 0.f;
#pragma unroll
        for (int f = 0; f < F_OUT; ++f) s = fmaf(qq[f], kk[f], s);
        d += __expf(fminf(s, 60.f));
    }
    dpart[nc * N_TOK + m] = d;
}

// ---------------------------------------------------------------------------
// Kernel C: invw[m] = aw[0] / sum_c dpart[c][m]   (fold softmax branch weight)
// ---------------------------------------------------------------------------
__global__ __launch_bounds__(256) void invw_kernel(
    const float* __restrict__ dpart, const float* __restrict__ aw,
    float* __restrict__ invw)
{
    int m = blockIdx.x * 256 + threadIdx.x;   // 20 blocks
    float d = 0.f;
#pragma unroll
    for (int c = 0; c < N_CHUNKS; ++c) d += dpart[c * N_TOK + m];
    invw[m] = aw[0] / d;
}

// ---------------------------------------------------------------------------
// Kernel D: main fused pass. Thread owns 2 rows n; loops over an m-chunk.
// coef(n,m) = w0*relu(s) + w1*sigmoid(s) + exp(s)*invw[m]
// opart[mc][n][f] = sum_{m in chunk} coef * v[f,m]
// ---------------------------------------------------------------------------
__global__ __launch_bounds__(256) void main_kernel(
    const float* __restrict__ Q, const float* __restrict__ K,
    const float* __restrict__ V, const float* __restrict__ invw,
    const float* __restrict__ aw, float* __restrict__ opart)
{
    int nTile = blockIdx.x % 10;
    int mc    = blockIdx.x / 10;             // 10*32 = 320 blocks
    int n0 = nTile * 512 + threadIdx.x;
    int n1 = n0 + 256;
    float w0 = aw[0], w1v = aw[1];

    float q0[12], q1[12];
    {
        const float4* qp = (const float4*)(Q + n0 * FP);
        float4 a = qp[0], b = qp[1], c = qp[2];
        q0[0]=a.x; q0[1]=a.y; q0[2]=a.z; q0[3]=a.w;
        q0[4]=b.x; q0[5]=b.y; q0[6]=b.z; q0[7]=b.w;
        q0[8]=c.x; q0[9]=c.y; q0[10]=c.z; q0[11]=c.w;
    }
    {
        const float4* qp = (const float4*)(Q + n1 * FP);
        float4 a = qp[0], b = qp[1], c = qp[2];
        q1[0]=a.x; q1[1]=a.y; q1[2]=a.z; q1[3]=a.w;
        q1[4]=b.x; q1[5]=b.y; q1[6]=b.z; q1[7]=b.w;
        q1[8]=c.x; q1[9]=c.y; q1[10]=c.z; q1[11]=c.w;
    }

    float acc0[F_OUT], acc1[F_OUT];
#pragma unroll
    for (int f = 0; f < F_OUT; ++f) { acc0[f] = 0.f; acc1[f] = 0.f; }

    int mstart = mc * MC_LEN;
    for (int m = mstart; m < mstart + MC_LEN; ++m) {
        const float4* kp = (const float4*)(K + m * FP);
        float4 ka = kp[0], kb = kp[1], kc = kp[2];
        float kk[12] = {ka.x, ka.y, ka.z, ka.w, kb.x, kb.y, kb.z, kb.w,
                        kc.x, kc.y, kc.z, kc.w};
        const float4* vp = (const float4*)(V + m * FP);
        float4 va = vp[0], vb = vp[1], vc = vp[2];
        float vv[12] = {va.x, va.y, va.z, va.w, vb.x, vb.y, vb.z, vb.w,
                        vc.x, vc.y, vc.z, vc.w};
        float iw = invw[m];

        float s0 = 0.f, s1 = 0.f;
#pragma unroll
        for (int f = 0; f < F_OUT; ++f) {
            s0 = fmaf(q0[f], kk[f], s0);
            s1 = fmaf(q1[f], kk[f], s1);
        }
        float r0 = fmaxf(s0, 0.f), r1 = fmaxf(s1, 0.f);
        float e0 = __expf(fminf(s0, 60.f));
        float e1 = __expf(fminf(s1, 60.f));
        float sg0 = e0 * __builtin_amdgcn_rcpf(1.f + e0);
        float sg1 = e1 * __builtin_amdgcn_rcpf(1.f + e1);
        float c0 = fmaf(e0, iw, fmaf(w1v, sg0, w0 * r0));
        float c1 = fmaf(e1, iw, fmaf(w1v, sg1, w0 * r1));
#pragma unroll
        for (int f = 0; f < F_OUT; ++f) {
            acc0[f] = fmaf(c0, vv[f], acc0[f]);
            acc1[f] = fmaf(c1, vv[f], acc1[f]);
        }
    }

    float* o0 = opart + (size_t)(mc * N_TOK + n0) * F_OUT;
    float* o1 = opart + (size_t)(mc * N_TOK + n1) * F_OUT;
#pragma unroll
    for (int f = 0; f < F_OUT; ++f) { o0[f] = acc0[f]; o1[f] = acc1[f]; }
}

// ---------------------------------------------------------------------------
// Kernel E: reduce m-chunk partials and write output with [T,F,H,W] transpose
// ---------------------------------------------------------------------------
__global__ __launch_bounds__(256) void reduce_kernel(
    const float* __restrict__ opart, float* __restrict__ out)
{
    int idx = blockIdx.x * 256 + threadIdx.x;    // 200 blocks * 256 = 51200
    unsigned un = (unsigned)idx / 10u;
    int n = (int)un;
    int f = idx - n * 10;
    float s = 0.f;
#pragma unroll
    for (int c = 0; c < M_CHUNKS; ++c) s += opart[c * (N_TOK * F_OUT) + idx];
    int t = n >> 10, p = n & 1023;
    out[((t * F_OUT + f) << 10) + p] = s;
}

// ---------------------------------------------------------------------------
extern "C" void kernel_launch(void* const* d_in, const int* in_sizes, int n_in,
                              void* d_out, int out_size, void* d_ws, size_t ws_size,
                              hipStream_t stream)
{
    const float* in1 = (const float*)d_in[0];   // input1 [1,5,64,32,32]
    const float* in2 = (const float*)d_in[1];   // input2
    const float* aw  = (const float*)d_in[2];   // act_weights [3]
    const float* w1  = (const float*)d_in[3];   // conv1_w [10,64]
    const float* b1  = (const float*)d_in[4];
    const float* w2  = (const float*)d_in[5];
    const float* b2  = (const float*)d_in[6];
    const float* w3  = (const float*)d_in[7];   // g3_w
    const float* b3  = (const float*)d_in[8];
    float* out = (float*)d_out;

    float* ws    = (float*)d_ws;
    float* Q     = ws;                       // N*FP
    float* K     = Q + N_TOK * FP;           // N*FP
    float* V     = K + N_TOK * FP;           // N*FP
    float* invw  = V + N_TOK * FP;           // N
    float* dpart = invw + N_TOK;             // 16*N
    float* opart = dpart + N_CHUNKS * N_TOK; // 32*N*10  (total ~7.3 MB)

    qkv_kernel<<<N_TOK / 256, 256, 0, stream>>>(in1, in2, w1, b1, w2, b2, w3, b3, Q, K, V);
    denom_kernel<<<20 * N_CHUNKS, 256, 0, stream>>>(Q, K, dpart);
    invw_kernel<<<N_TOK / 256, 256, 0, stream>>>(dpart, aw, invw);
    main_kernel<<<10 * M_CHUNKS, 256, 0, stream>>>(Q, K, V, invw, aw, opart);
    reduce_kernel<<<(N_TOK * F_OUT) / 256, 256, 0, stream>>>(opart, out);
}

// Round 2
// 151.209 us; speedup vs baseline: 1.6139x; 1.6139x over previous
//
#include <hip/hip_runtime.h>

// Problem constants: B=1, T=5, C=64, H=W=32, F=10
#define N_TOK   5120      // T*H*W
#define C_IN    64
#define F_OUT   10
#define FP      12        // padded row stride for q/k/v rows (3 x float4)

// ---------------------------------------------------------------------------
// Kernel A: q = W1*x1+b1, k = W2*x2+b2, v = W3*x1+b3  -> [N][FP] rows
// 80 blocks; block = 64 tokens x 4 c-groups (16 channels each) + LDS reduce.
// ---------------------------------------------------------------------------
__global__ __launch_bounds__(256) void qkv_kernel(
    const float* __restrict__ x1, const float* __restrict__ x2,
    const float* __restrict__ w1, const float* __restrict__ b1,
    const float* __restrict__ w2, const float* __restrict__ b2,
    const float* __restrict__ w3, const float* __restrict__ b3,
    float* __restrict__ Q, float* __restrict__ K, float* __restrict__ V)
{
    __shared__ float sw[3][C_IN][F_OUT];     // [arr][c][f], broadcast reads
    __shared__ float psum[3][4][64][11];     // f-dim padded to 11 (bank spread)
    int tid = threadIdx.x;
    for (int i = tid; i < C_IN * F_OUT; i += 256) {
        int f = i >> 6, c = i & 63;          // w layout [f][c]
        sw[0][c][f] = w1[i];
        sw[1][c][f] = w2[i];
        sw[2][c][f] = w3[i];
    }
    __syncthreads();

    int g = tid >> 6, l = tid & 63;
    int n = blockIdx.x * 64 + l;
    int t = n >> 10, p = n & 1023;
    const float* x1p = x1 + t * (C_IN * 1024) + p;
    const float* x2p = x2 + t * (C_IN * 1024) + p;

    float qa[F_OUT], ka[F_OUT], va[F_OUT];
#pragma unroll
    for (int f = 0; f < F_OUT; ++f) { qa[f] = 0.f; ka[f] = 0.f; va[f] = 0.f; }

    int c0 = g * 16;
#pragma unroll 4
    for (int cc = 0; cc < 16; ++cc) {
        int c = c0 + cc;
        float a = x1p[c * 1024];
        float b = x2p[c * 1024];
#pragma unroll
        for (int f = 0; f < F_OUT; ++f) {
            qa[f] = fmaf(sw[0][c][f], a, qa[f]);
            ka[f] = fmaf(sw[1][c][f], b, ka[f]);
            va[f] = fmaf(sw[2][c][f], a, va[f]);
        }
    }
#pragma unroll
    for (int f = 0; f < F_OUT; ++f) {
        psum[0][g][l][f] = qa[f];
        psum[1][g][l][f] = ka[f];
        psum[2][g][l][f] = va[f];
    }
    __syncthreads();

    // reduce 4 c-groups + bias, write [n][f]
    for (int i = tid; i < 3 * 64 * F_OUT; i += 256) {
        int a = i / 640;
        int rem = i - a * 640;
        int nl = rem / 10, f = rem - nl * 10;
        float s = psum[a][0][nl][f] + psum[a][1][nl][f] +
                  psum[a][2][nl][f] + psum[a][3][nl][f];
        const float* bias = (a == 0) ? b1 : (a == 1) ? b2 : b3;
        float* dst = (a == 0) ? Q : (a == 1) ? K : V;
        dst[(blockIdx.x * 64 + nl) * FP + f] = s + bias[f];
    }
    // zero pads so float4 row reads are clean
    for (int i = tid; i < 3 * 64 * 2; i += 256) {
        int a = i / 128;
        int rem = i - a * 128;
        int nl = rem >> 1, pd = rem & 1;
        float* dst = (a == 0) ? Q : (a == 1) ? K : V;
        dst[(blockIdx.x * 64 + nl) * FP + 10 + pd] = 0.f;
    }
}

// ---------------------------------------------------------------------------
// Kernel B: partial softmax denominators. Thread owns TWO m-columns
// (amortize uniform q-row loads); grid = 10 mTiles x nchunks.
// ---------------------------------------------------------------------------
__global__ __launch_bounds__(256) void denom_kernel(
    const float* __restrict__ Q, const float* __restrict__ K,
    float* __restrict__ dpart, int nclen)
{
    int mTile = blockIdx.x % 10;
    int nc    = blockIdx.x / 10;
    int m0 = mTile * 512 + threadIdx.x;
    int m1 = m0 + 256;

    float k0[12], k1[12];
    {
        const float4* kp = (const float4*)(K + m0 * FP);
        float4 a = kp[0], b = kp[1], c = kp[2];
        k0[0]=a.x; k0[1]=a.y; k0[2]=a.z; k0[3]=a.w;
        k0[4]=b.x; k0[5]=b.y; k0[6]=b.z; k0[7]=b.w;
        k0[8]=c.x; k0[9]=c.y; k0[10]=c.z; k0[11]=c.w;
    }
    {
        const float4* kp = (const float4*)(K + m1 * FP);
        float4 a = kp[0], b = kp[1], c = kp[2];
        k1[0]=a.x; k1[1]=a.y; k1[2]=a.z; k1[3]=a.w;
        k1[4]=b.x; k1[5]=b.y; k1[6]=b.z; k1[7]=b.w;
        k1[8]=c.x; k1[9]=c.y; k1[10]=c.z; k1[11]=c.w;
    }

    float d0 = 0.f, d1 = 0.f;
    int n0 = nc * nclen;
#pragma unroll 2
    for (int n = n0; n < n0 + nclen; ++n) {
        const float4* qp = (const float4*)(Q + n * FP);
        float4 qa = qp[0], qb = qp[1], qc = qp[2];
        float qq[12] = {qa.x, qa.y, qa.z, qa.w, qb.x, qb.y, qb.z, qb.w,
                        qc.x, qc.y, qc.z, qc.w};
        float s0 = 0.f, s1 = 0.f;
#pragma unroll
        for (int f = 0; f < F_OUT; ++f) {
            s0 = fmaf(qq[f], k0[f], s0);
            s1 = fmaf(qq[f], k1[f], s1);
        }
        d0 += __expf(fminf(s0, 60.f));
        d1 += __expf(fminf(s1, 60.f));
    }
    dpart[nc * N_TOK + m0] = d0;
    dpart[nc * N_TOK + m1] = d1;
}

// ---------------------------------------------------------------------------
// Kernel C: invw[m] = aw[0] / sum_c dpart[c][m]
// ---------------------------------------------------------------------------
__global__ __launch_bounds__(256) void invw_kernel(
    const float* __restrict__ dpart, const float* __restrict__ aw,
    float* __restrict__ invw, int nchunks)
{
    int m = blockIdx.x * 256 + threadIdx.x;
    float d = 0.f;
#pragma unroll 8
    for (int c = 0; c < nchunks; ++c) d += dpart[c * N_TOK + m];
    invw[m] = aw[0] / d;
}

// ---------------------------------------------------------------------------
// Kernel D: main fused pass. Thread owns FOUR rows n (amortize uniform K/V
// loads: 7 loads serve ~100 lane-ops). Grid = 5 nTiles x mchunks.
// coef(n,m) = w0*relu(s) + w1*sigmoid(s) + exp(s)*invw[m]
// ---------------------------------------------------------------------------
__global__ __launch_bounds__(256) void main_kernel(
    const float* __restrict__ Q, const float* __restrict__ K,
    const float* __restrict__ V, const float* __restrict__ invw,
    const float* __restrict__ aw, float* __restrict__ opart, int mclen)
{
    int nTile = blockIdx.x % 5;
    int mc    = blockIdx.x / 5;
    int nb = nTile * 1024 + threadIdx.x;
    float w0 = aw[0], w1v = aw[1];

    float q[4][12];
#pragma unroll
    for (int r = 0; r < 4; ++r) {
        const float4* qp = (const float4*)(Q + (nb + r * 256) * FP);
        float4 a = qp[0], b = qp[1], c = qp[2];
        q[r][0]=a.x; q[r][1]=a.y; q[r][2]=a.z; q[r][3]=a.w;
        q[r][4]=b.x; q[r][5]=b.y; q[r][6]=b.z; q[r][7]=b.w;
        q[r][8]=c.x; q[r][9]=c.y; q[r][10]=c.z; q[r][11]=c.w;
    }

    float acc[4][F_OUT];
#pragma unroll
    for (int r = 0; r < 4; ++r)
#pragma unroll
        for (int f = 0; f < F_OUT; ++f) acc[r][f] = 0.f;

    int mstart = mc * mclen;
#pragma unroll 2
    for (int m = mstart; m < mstart + mclen; ++m) {
        const float4* kp = (const float4*)(K + m * FP);
        float4 ka = kp[0], kb = kp[1], kc = kp[2];
        float kk[12] = {ka.x, ka.y, ka.z, ka.w, kb.x, kb.y, kb.z, kb.w,
                        kc.x, kc.y, kc.z, kc.w};
        const float4* vp = (const float4*)(V + m * FP);
        float4 va = vp[0], vb = vp[1], vc = vp[2];
        float vv[12] = {va.x, va.y, va.z, va.w, vb.x, vb.y, vb.z, vb.w,
                        vc.x, vc.y, vc.z, vc.w};
        float iw = invw[m];

#pragma unroll
        for (int r = 0; r < 4; ++r) {
            float s = 0.f;
#pragma unroll
            for (int f = 0; f < F_OUT; ++f) s = fmaf(q[r][f], kk[f], s);
            float rl = fmaxf(s, 0.f);
            float e  = __expf(fminf(s, 60.f));
            float sg = e * __builtin_amdgcn_rcpf(1.f + e);
            float cf = fmaf(e, iw, fmaf(w1v, sg, w0 * rl));
#pragma unroll
            for (int f = 0; f < F_OUT; ++f) acc[r][f] = fmaf(cf, vv[f], acc[r][f]);
        }
    }

#pragma unroll
    for (int r = 0; r < 4; ++r) {
        float2* o = (float2*)(opart + (size_t)(mc * N_TOK + nb + r * 256) * F_OUT);
#pragma unroll
        for (int f = 0; f < 5; ++f)
            o[f] = make_float2(acc[r][2 * f], acc[r][2 * f + 1]);
    }
}

// ---------------------------------------------------------------------------
// Kernel E: reduce m-chunk partials; write with [T,F,H,W] transpose
// ---------------------------------------------------------------------------
__global__ __launch_bounds__(256) void reduce_kernel(
    const float* __restrict__ opart, float* __restrict__ out, int mchunks)
{
    int idx = blockIdx.x * 256 + threadIdx.x;    // 200 blocks * 256 = 51200
    float s = 0.f;
#pragma unroll 8
    for (int c = 0; c < mchunks; ++c) s += opart[c * (N_TOK * F_OUT) + idx];
    unsigned un = (unsigned)idx / 10u;
    int n = (int)un;
    int f = idx - n * 10;
    int t = n >> 10, p = n & 1023;
    out[((t * F_OUT + f) << 10) + p] = s;
}

// ---------------------------------------------------------------------------
extern "C" void kernel_launch(void* const* d_in, const int* in_sizes, int n_in,
                              void* d_out, int out_size, void* d_ws, size_t ws_size,
                              hipStream_t stream)
{
    const float* in1 = (const float*)d_in[0];
    const float* in2 = (const float*)d_in[1];
    const float* aw  = (const float*)d_in[2];
    const float* w1  = (const float*)d_in[3];
    const float* b1  = (const float*)d_in[4];
    const float* w2  = (const float*)d_in[5];
    const float* b2  = (const float*)d_in[6];
    const float* w3  = (const float*)d_in[7];
    const float* b3  = (const float*)d_in[8];
    float* out = (float*)d_out;

    // runtime chunk config bounded by ws_size (fallback = proven R1 footprint)
    int nchunks, mchunks;
    if (ws_size >= (size_t)30 << 20)      { nchunks = 64; mchunks = 128; }
    else if (ws_size >= (size_t)16 << 20) { nchunks = 64; mchunks = 64;  }
    else                                  { nchunks = 16; mchunks = 32;  }
    int nclen = N_TOK / nchunks;
    int mclen = N_TOK / mchunks;

    float* ws    = (float*)d_ws;
    float* Q     = ws;                        // N*FP
    float* K     = Q + N_TOK * FP;
    float* V     = K + N_TOK * FP;
    float* invw  = V + N_TOK * FP;            // N
    float* dpart = invw + N_TOK;              // nchunks*N
    float* opart = dpart + nchunks * N_TOK;   // mchunks*N*10

    qkv_kernel<<<N_TOK / 64, 256, 0, stream>>>(in1, in2, w1, b1, w2, b2, w3, b3, Q, K, V);
    denom_kernel<<<10 * nchunks, 256, 0, stream>>>(Q, K, dpart, nclen);
    invw_kernel<<<N_TOK / 256, 256, 0, stream>>>(dpart, aw, invw, nchunks);
    main_kernel<<<5 * mchunks, 256, 0, stream>>>(Q, K, V, invw, aw, opart, mclen);
    reduce_kernel<<<(N_TOK * F_OUT) / 256, 256, 0, stream>>>(opart, out, mchunks);
}

// Round 3
// 137.674 us; speedup vs baseline: 1.7726x; 1.0983x over previous
//
#include <hip/hip_runtime.h>

// Problem constants: B=1, T=5, C=64, H=W=32, F=10
#define N_TOK   5120      // T*H*W
#define C_IN    64
#define F_OUT   10
#define FP      12        // padded row stride for q/k/v rows (3 x float4)

#define DTILE   80        // denom: Q rows staged per LDS tile
#define MTILE   40        // main: K/V rows staged per LDS tile

// ---------------------------------------------------------------------------
// Kernel A: q = W1*x1+b1, k = W2*x2+b2, v = W3*x1+b3  -> [N][FP] rows
// 80 blocks; block = 64 tokens x 4 c-groups (16 channels each) + LDS reduce.
// ---------------------------------------------------------------------------
__global__ __launch_bounds__(256) void qkv_kernel(
    const float* __restrict__ x1, const float* __restrict__ x2,
    const float* __restrict__ w1, const float* __restrict__ b1,
    const float* __restrict__ w2, const float* __restrict__ b2,
    const float* __restrict__ w3, const float* __restrict__ b3,
    float* __restrict__ Q, float* __restrict__ K, float* __restrict__ V)
{
    __shared__ float sw[3][C_IN][F_OUT];     // [arr][c][f], broadcast reads
    __shared__ float psum[3][4][64][11];     // f-dim padded to 11 (bank spread)
    int tid = threadIdx.x;
    for (int i = tid; i < C_IN * F_OUT; i += 256) {
        int f = i >> 6, c = i & 63;          // w layout [f][c]
        sw[0][c][f] = w1[i];
        sw[1][c][f] = w2[i];
        sw[2][c][f] = w3[i];
    }
    __syncthreads();

    int g = tid >> 6, l = tid & 63;
    int n = blockIdx.x * 64 + l;
    int t = n >> 10, p = n & 1023;
    const float* x1p = x1 + t * (C_IN * 1024) + p;
    const float* x2p = x2 + t * (C_IN * 1024) + p;

    float qa[F_OUT], ka[F_OUT], va[F_OUT];
#pragma unroll
    for (int f = 0; f < F_OUT; ++f) { qa[f] = 0.f; ka[f] = 0.f; va[f] = 0.f; }

    int c0 = g * 16;
#pragma unroll 4
    for (int cc = 0; cc < 16; ++cc) {
        int c = c0 + cc;
        float a = x1p[c * 1024];
        float b = x2p[c * 1024];
#pragma unroll
        for (int f = 0; f < F_OUT; ++f) {
            qa[f] = fmaf(sw[0][c][f], a, qa[f]);
            ka[f] = fmaf(sw[1][c][f], b, ka[f]);
            va[f] = fmaf(sw[2][c][f], a, va[f]);
        }
    }
#pragma unroll
    for (int f = 0; f < F_OUT; ++f) {
        psum[0][g][l][f] = qa[f];
        psum[1][g][l][f] = ka[f];
        psum[2][g][l][f] = va[f];
    }
    __syncthreads();

    // reduce 4 c-groups + bias, write [n][f]
    for (int i = tid; i < 3 * 64 * F_OUT; i += 256) {
        int a = i / 640;
        int rem = i - a * 640;
        int nl = rem / 10, f = rem - nl * 10;
        float s = psum[a][0][nl][f] + psum[a][1][nl][f] +
                  psum[a][2][nl][f] + psum[a][3][nl][f];
        const float* bias = (a == 0) ? b1 : (a == 1) ? b2 : b3;
        float* dst = (a == 0) ? Q : (a == 1) ? K : V;
        dst[(blockIdx.x * 64 + nl) * FP + f] = s + bias[f];
    }
    // zero pads so float4 row reads are clean
    for (int i = tid; i < 3 * 64 * 2; i += 256) {
        int a = i / 128;
        int rem = i - a * 128;
        int nl = rem >> 1, pd = rem & 1;
        float* dst = (a == 0) ? Q : (a == 1) ? K : V;
        dst[(blockIdx.x * 64 + nl) * FP + 10 + pd] = 0.f;
    }
}

// ---------------------------------------------------------------------------
// Kernel B: partial softmax denominators. Thread owns TWO m-columns (K in
// registers); Q rows staged through LDS in tiles of DTILE (coalesced float4
// loads, broadcast ds_read_b128 in the inner loop).
// ---------------------------------------------------------------------------
__global__ __launch_bounds__(256) void denom_kernel(
    const float* __restrict__ Q, const float* __restrict__ K,
    float* __restrict__ dpart, int nclen)
{
    int mTile = blockIdx.x % 10;
    int nc    = blockIdx.x / 10;
    int tid   = threadIdx.x;
    int m0 = mTile * 512 + tid;
    int m1 = m0 + 256;

    float k0[12], k1[12];
    {
        const float4* kp = (const float4*)(K + m0 * FP);
        float4 a = kp[0], b = kp[1], c = kp[2];
        k0[0]=a.x; k0[1]=a.y; k0[2]=a.z; k0[3]=a.w;
        k0[4]=b.x; k0[5]=b.y; k0[6]=b.z; k0[7]=b.w;
        k0[8]=c.x; k0[9]=c.y; k0[10]=c.z; k0[11]=c.w;
    }
    {
        const float4* kp = (const float4*)(K + m1 * FP);
        float4 a = kp[0], b = kp[1], c = kp[2];
        k1[0]=a.x; k1[1]=a.y; k1[2]=a.z; k1[3]=a.w;
        k1[4]=b.x; k1[5]=b.y; k1[6]=b.z; k1[7]=b.w;
        k1[8]=c.x; k1[9]=c.y; k1[10]=c.z; k1[11]=c.w;
    }

    __shared__ __align__(16) float sq[DTILE * FP];   // 960 floats

    float d0 = 0.f, d1 = 0.f;
    int n0 = nc * nclen;
    for (int base = n0; base < n0 + nclen; base += DTILE) {
        __syncthreads();
        if (tid < DTILE * FP / 4)   // 240 coalesced float4 loads
            ((float4*)sq)[tid] = ((const float4*)(Q + base * FP))[tid];
        __syncthreads();
#pragma unroll 4
        for (int j = 0; j < DTILE; ++j) {
            const float4* qp = (const float4*)(sq + j * FP);
            float4 qa = qp[0], qb = qp[1], qc = qp[2];
            float qq[12] = {qa.x, qa.y, qa.z, qa.w, qb.x, qb.y, qb.z, qb.w,
                            qc.x, qc.y, qc.z, qc.w};
            float s0 = 0.f, s1 = 0.f;
#pragma unroll
            for (int f = 0; f < F_OUT; ++f) {
                s0 = fmaf(qq[f], k0[f], s0);
                s1 = fmaf(qq[f], k1[f], s1);
            }
            d0 += __expf(fminf(s0, 60.f));
            d1 += __expf(fminf(s1, 60.f));
        }
    }
    dpart[nc * N_TOK + m0] = d0;
    dpart[nc * N_TOK + m1] = d1;
}

// ---------------------------------------------------------------------------
// Kernel C: invw[m] = aw[0] / sum_c dpart[c][m]
// ---------------------------------------------------------------------------
__global__ __launch_bounds__(256) void invw_kernel(
    const float* __restrict__ dpart, const float* __restrict__ aw,
    float* __restrict__ invw, int nchunks)
{
    int m = blockIdx.x * 256 + threadIdx.x;
    float d = 0.f;
#pragma unroll 8
    for (int c = 0; c < nchunks; ++c) d += dpart[c * N_TOK + m];
    invw[m] = aw[0] / d;
}

// ---------------------------------------------------------------------------
// Kernel D: main fused pass. Thread owns FOUR rows n; K/V/invw staged through
// LDS in tiles of MTILE (coalesced float4 loads, broadcast reads inner loop).
// coef(n,m) = w0*relu(s) + w1*sigmoid(s) + exp(s)*invw[m]
// ---------------------------------------------------------------------------
__global__ __launch_bounds__(256) void main_kernel(
    const float* __restrict__ Q, const float* __restrict__ K,
    const float* __restrict__ V, const float* __restrict__ invw,
    const float* __restrict__ aw, float* __restrict__ opart, int mclen)
{
    int nTile = blockIdx.x % 5;
    int mc    = blockIdx.x / 5;
    int tid   = threadIdx.x;
    int nb = nTile * 1024 + tid;
    float w0 = aw[0], w1v = aw[1];

    float q[4][12];
#pragma unroll
    for (int r = 0; r < 4; ++r) {
        const float4* qp = (const float4*)(Q + (nb + r * 256) * FP);
        float4 a = qp[0], b = qp[1], c = qp[2];
        q[r][0]=a.x; q[r][1]=a.y; q[r][2]=a.z; q[r][3]=a.w;
        q[r][4]=b.x; q[r][5]=b.y; q[r][6]=b.z; q[r][7]=b.w;
        q[r][8]=c.x; q[r][9]=c.y; q[r][10]=c.z; q[r][11]=c.w;
    }

    float acc[4][F_OUT];
#pragma unroll
    for (int r = 0; r < 4; ++r)
#pragma unroll
        for (int f = 0; f < F_OUT; ++f) acc[r][f] = 0.f;

    __shared__ __align__(16) float sk[MTILE * FP];   // 480 floats
    __shared__ __align__(16) float sv[MTILE * FP];   // 480 floats
    __shared__ __align__(16) float siw[MTILE];       // 40 floats

    int mstart = mc * mclen;
    for (int mbase = mstart; mbase < mstart + mclen; mbase += MTILE) {
        __syncthreads();
        if (tid < 120)
            ((float4*)sk)[tid] = ((const float4*)(K + mbase * FP))[tid];
        else if (tid < 240)
            ((float4*)sv)[tid - 120] = ((const float4*)(V + mbase * FP))[tid - 120];
        else if (tid < 250)
            ((float4*)siw)[tid - 240] = ((const float4*)(invw + mbase))[tid - 240];
        __syncthreads();

#pragma unroll 2
        for (int j = 0; j < MTILE; ++j) {
            const float4* kp = (const float4*)(sk + j * FP);
            float4 ka = kp[0], kb = kp[1], kc = kp[2];
            float kk[12] = {ka.x, ka.y, ka.z, ka.w, kb.x, kb.y, kb.z, kb.w,
                            kc.x, kc.y, kc.z, kc.w};
            const float4* vp = (const float4*)(sv + j * FP);
            float4 va = vp[0], vb = vp[1], vc = vp[2];
            float vv[12] = {va.x, va.y, va.z, va.w, vb.x, vb.y, vb.z, vb.w,
                            vc.x, vc.y, vc.z, vc.w};
            float iw = siw[j];

#pragma unroll
            for (int r = 0; r < 4; ++r) {
                float s = 0.f;
#pragma unroll
                for (int f = 0; f < F_OUT; ++f) s = fmaf(q[r][f], kk[f], s);
                float rl = fmaxf(s, 0.f);
                float e  = __expf(fminf(s, 60.f));
                float sg = e * __builtin_amdgcn_rcpf(1.f + e);
                float cf = fmaf(e, iw, fmaf(w1v, sg, w0 * rl));
#pragma unroll
                for (int f = 0; f < F_OUT; ++f) acc[r][f] = fmaf(cf, vv[f], acc[r][f]);
            }
        }
    }

#pragma unroll
    for (int r = 0; r < 4; ++r) {
        float2* o = (float2*)(opart + (size_t)(mc * N_TOK + nb + r * 256) * F_OUT);
#pragma unroll
        for (int f = 0; f < 5; ++f)
            o[f] = make_float2(acc[r][2 * f], acc[r][2 * f + 1]);
    }
}

// ---------------------------------------------------------------------------
// Kernel E: reduce m-chunk partials; write with [T,F,H,W] transpose
// ---------------------------------------------------------------------------
__global__ __launch_bounds__(256) void reduce_kernel(
    const float* __restrict__ opart, float* __restrict__ out, int mchunks)
{
    int idx = blockIdx.x * 256 + threadIdx.x;    // 200 blocks * 256 = 51200
    float s = 0.f;
#pragma unroll 8
    for (int c = 0; c < mchunks; ++c) s += opart[c * (N_TOK * F_OUT) + idx];
    unsigned un = (unsigned)idx / 10u;
    int n = (int)un;
    int f = idx - n * 10;
    int t = n >> 10, p = n & 1023;
    out[((t * F_OUT + f) << 10) + p] = s;
}

// ---------------------------------------------------------------------------
extern "C" void kernel_launch(void* const* d_in, const int* in_sizes, int n_in,
                              void* d_out, int out_size, void* d_ws, size_t ws_size,
                              hipStream_t stream)
{
    const float* in1 = (const float*)d_in[0];
    const float* in2 = (const float*)d_in[1];
    const float* aw  = (const float*)d_in[2];
    const float* w1  = (const float*)d_in[3];
    const float* b1  = (const float*)d_in[4];
    const float* w2  = (const float*)d_in[5];
    const float* b2  = (const float*)d_in[6];
    const float* w3  = (const float*)d_in[7];
    const float* b3  = (const float*)d_in[8];
    float* out = (float*)d_out;

    // runtime chunk config bounded by ws_size; chunk lengths stay multiples of
    // DTILE / MTILE so the LDS tile loops are exact.
    int nchunks, mchunks;
    if (ws_size >= (size_t)30 << 20)      { nchunks = 64; mchunks = 128; }
    else if (ws_size >= (size_t)16 << 20) { nchunks = 64; mchunks = 64;  }
    else                                  { nchunks = 16; mchunks = 32;  }
    int nclen = N_TOK / nchunks;   // 80 / 80 / 320
    int mclen = N_TOK / mchunks;   // 40 / 80 / 160

    float* ws    = (float*)d_ws;
    float* Q     = ws;                        // N*FP
    float* K     = Q + N_TOK * FP;
    float* V     = K + N_TOK * FP;
    float* invw  = V + N_TOK * FP;            // N
    float* dpart = invw + N_TOK;              // nchunks*N
    float* opart = dpart + nchunks * N_TOK;   // mchunks*N*10

    qkv_kernel<<<N_TOK / 64, 256, 0, stream>>>(in1, in2, w1, b1, w2, b2, w3, b3, Q, K, V);
    denom_kernel<<<10 * nchunks, 256, 0, stream>>>(Q, K, dpart, nclen);
    invw_kernel<<<N_TOK / 256, 256, 0, stream>>>(dpart, aw, invw, nchunks);
    main_kernel<<<5 * mchunks, 256, 0, stream>>>(Q, K, V, invw, aw, opart, mclen);
    reduce_kernel<<<(N_TOK * F_OUT) / 256, 256, 0, stream>>>(opart, out, mchunks);
}

// Round 4
// 137.000 us; speedup vs baseline: 1.7813x; 1.0049x over previous
//
#include <hip/hip_runtime.h>

// Problem constants: B=1, T=5, C=64, H=W=32, F=10
#define N_TOK   5120      // T*H*W
#define C_IN    64
#define F_OUT   10
#define FP      12        // padded row stride: [0..9]=data, [10]=invw (K only)

#define DTILE   40        // denom: Q rows staged per LDS tile
#define MTILE   40        // main: K/V rows staged per LDS tile

// ---------------------------------------------------------------------------
// Kernel A: q/k/v pointwise conv. Thread = one (n, f, arr) output value.
// 600 blocks: arr(3) x f(10) x nblk(20). 64 coalesced loads + 64 FMA each.
// ---------------------------------------------------------------------------
__global__ __launch_bounds__(256) void qkv_kernel(
    const float* __restrict__ x1, const float* __restrict__ x2,
    const float* __restrict__ w1, const float* __restrict__ b1,
    const float* __restrict__ w2, const float* __restrict__ b2,
    const float* __restrict__ w3, const float* __restrict__ b3,
    float* __restrict__ Q, float* __restrict__ K, float* __restrict__ V)
{
    int arr = blockIdx.x / 200;            // 0=Q, 1=K, 2=V
    int rem = blockIdx.x - arr * 200;
    int f   = rem / 20;
    int nbk = rem - f * 20;
    int n   = nbk * 256 + threadIdx.x;
    int t = n >> 10, p = n & 1023;

    const float* x    = (arr == 1) ? x2 : x1;
    const float* w    = (arr == 0) ? w1 : (arr == 1) ? w2 : w3;
    const float* bias = (arr == 0) ? b1 : (arr == 1) ? b2 : b3;
    float*       dst  = (arr == 0) ? Q  : (arr == 1) ? K  : V;

    const float* xp = x + t * (C_IN * 1024) + p;
    const float* wr = w + f * C_IN;

    float4 wv[16];
#pragma unroll
    for (int i = 0; i < 16; ++i) wv[i] = ((const float4*)wr)[i];

    float acc = 0.f;
#pragma unroll
    for (int i = 0; i < 16; ++i) {
        acc = fmaf(wv[i].x, xp[(4 * i + 0) * 1024], acc);
        acc = fmaf(wv[i].y, xp[(4 * i + 1) * 1024], acc);
        acc = fmaf(wv[i].z, xp[(4 * i + 2) * 1024], acc);
        acc = fmaf(wv[i].w, xp[(4 * i + 3) * 1024], acc);
    }
    dst[n * FP + f] = acc + bias[f];
}

// ---------------------------------------------------------------------------
// Kernel B: partial softmax denominators. Thread owns FOUR m-columns (K in
// regs; 3 broadcast LDS reads per j serve 104 VALU cyc). Grid = 5 x nchunks.
// ---------------------------------------------------------------------------
__global__ __launch_bounds__(256) void denom_kernel(
    const float* __restrict__ Q, const float* __restrict__ K,
    float* __restrict__ dpart, int nclen)
{
    int mTile = blockIdx.x % 5;
    int nc    = blockIdx.x / 5;
    int tid   = threadIdx.x;
    int m0 = mTile * 1024 + tid;

    float kk[4][10];
#pragma unroll
    for (int c = 0; c < 4; ++c) {
        const float* kp = K + (m0 + c * 256) * FP;
        float4 a = ((const float4*)kp)[0];
        float4 b = ((const float4*)kp)[1];
        float2 e = ((const float2*)kp)[4];
        kk[c][0]=a.x; kk[c][1]=a.y; kk[c][2]=a.z; kk[c][3]=a.w;
        kk[c][4]=b.x; kk[c][5]=b.y; kk[c][6]=b.z; kk[c][7]=b.w;
        kk[c][8]=e.x; kk[c][9]=e.y;
    }

    __shared__ __align__(16) float sq[DTILE * FP];   // 480 floats

    float d[4] = {0.f, 0.f, 0.f, 0.f};
    int n0 = nc * nclen;
    for (int base = n0; base < n0 + nclen; base += DTILE) {
        __syncthreads();
        if (tid < DTILE * FP / 4)   // 120 coalesced float4 loads
            ((float4*)sq)[tid] = ((const float4*)(Q + base * FP))[tid];
        __syncthreads();
#pragma unroll 2
        for (int j = 0; j < DTILE; ++j) {
            const float4* qp = (const float4*)(sq + j * FP);
            float4 qa = qp[0], qb = qp[1], qc = qp[2];
            float qq[10] = {qa.x, qa.y, qa.z, qa.w, qb.x, qb.y, qb.z, qb.w,
                            qc.x, qc.y};
#pragma unroll
            for (int c = 0; c < 4; ++c) {
                float s = 0.f;
#pragma unroll
                for (int f = 0; f < F_OUT; ++f) s = fmaf(qq[f], kk[c][f], s);
                d[c] += __expf(fminf(s, 60.f));
            }
        }
    }
#pragma unroll
    for (int c = 0; c < 4; ++c) dpart[nc * N_TOK + m0 + c * 256] = d[c];
}

// ---------------------------------------------------------------------------
// Kernel C: K[m][10] = aw[0] / sum_c dpart[c][m]   (invw packed into K row)
// ---------------------------------------------------------------------------
__global__ __launch_bounds__(256) void invw_kernel(
    const float* __restrict__ dpart, const float* __restrict__ aw,
    float* __restrict__ K, int nchunks)
{
    int m = blockIdx.x * 256 + threadIdx.x;
    float d = 0.f;
#pragma unroll 8
    for (int c = 0; c < nchunks; ++c) d += dpart[c * N_TOK + m];
    K[m * FP + 10] = aw[0] / d;
}

// ---------------------------------------------------------------------------
// Kernel D: main fused pass. Thread owns FIVE rows n; K/V staged through LDS
// (invw rides in K row slot 10 -> 6 broadcast reads serve ~290 VALU cyc).
// coef(n,m) = w0*relu(s) + w1*sigmoid(s) + exp(s)*invw[m]
// ---------------------------------------------------------------------------
__global__ __launch_bounds__(256) void main_kernel(
    const float* __restrict__ Q, const float* __restrict__ K,
    const float* __restrict__ V, const float* __restrict__ aw,
    float* __restrict__ opart, int mclen)
{
    int nTile = blockIdx.x % 4;
    int mc    = blockIdx.x / 4;
    int tid   = threadIdx.x;
    int nb = nTile * 1280 + tid;
    float w0 = aw[0], w1v = aw[1];

    float q[5][10];
#pragma unroll
    for (int r = 0; r < 5; ++r) {
        const float* qp = Q + (nb + r * 256) * FP;
        float4 a = ((const float4*)qp)[0];
        float4 b = ((const float4*)qp)[1];
        float2 e = ((const float2*)qp)[4];
        q[r][0]=a.x; q[r][1]=a.y; q[r][2]=a.z; q[r][3]=a.w;
        q[r][4]=b.x; q[r][5]=b.y; q[r][6]=b.z; q[r][7]=b.w;
        q[r][8]=e.x; q[r][9]=e.y;
    }

    float acc[5][F_OUT];
#pragma unroll
    for (int r = 0; r < 5; ++r)
#pragma unroll
        for (int f = 0; f < F_OUT; ++f) acc[r][f] = 0.f;

    __shared__ __align__(16) float sk[MTILE * FP];   // 480 floats
    __shared__ __align__(16) float sv[MTILE * FP];   // 480 floats

    int mstart = mc * mclen;
    for (int mbase = mstart; mbase < mstart + mclen; mbase += MTILE) {
        __syncthreads();
        if (tid < 120)
            ((float4*)sk)[tid] = ((const float4*)(K + mbase * FP))[tid];
        else if (tid < 240)
            ((float4*)sv)[tid - 120] = ((const float4*)(V + mbase * FP))[tid - 120];
        __syncthreads();

#pragma unroll 2
        for (int j = 0; j < MTILE; ++j) {
            const float4* kp = (const float4*)(sk + j * FP);
            float4 ka = kp[0], kb = kp[1], kc = kp[2];
            float kk[10] = {ka.x, ka.y, ka.z, ka.w, kb.x, kb.y, kb.z, kb.w,
                            kc.x, kc.y};
            float iw = kc.z;                     // invw packed at slot 10
            const float4* vp = (const float4*)(sv + j * FP);
            float4 va = vp[0], vb = vp[1], vc = vp[2];
            float vv[10] = {va.x, va.y, va.z, va.w, vb.x, vb.y, vb.z, vb.w,
                            vc.x, vc.y};

#pragma unroll
            for (int r = 0; r < 5; ++r) {
                float s = 0.f;
#pragma unroll
                for (int f = 0; f < F_OUT; ++f) s = fmaf(q[r][f], kk[f], s);
                float rl = fmaxf(s, 0.f);
                float e  = __expf(fminf(s, 60.f));
                float sg = e * __builtin_amdgcn_rcpf(1.f + e);
                float cf = fmaf(e, iw, fmaf(w1v, sg, w0 * rl));
#pragma unroll
                for (int f = 0; f < F_OUT; ++f) acc[r][f] = fmaf(cf, vv[f], acc[r][f]);
            }
        }
    }

#pragma unroll
    for (int r = 0; r < 5; ++r) {
        float2* o = (float2*)(opart + (size_t)(mc * N_TOK + nb + r * 256) * F_OUT);
#pragma unroll
        for (int f = 0; f < 5; ++f)
            o[f] = make_float2(acc[r][2 * f], acc[r][2 * f + 1]);
    }
}

// ---------------------------------------------------------------------------
// Kernel E: reduce m-chunk partials; write with [T,F,H,W] transpose
// ---------------------------------------------------------------------------
__global__ __launch_bounds__(256) void reduce_kernel(
    const float* __restrict__ opart, float* __restrict__ out, int mchunks)
{
    int idx = blockIdx.x * 256 + threadIdx.x;    // 200 blocks * 256 = 51200
    float s = 0.f;
#pragma unroll 16
    for (int c = 0; c < mchunks; ++c) s += opart[c * (N_TOK * F_OUT) + idx];
    unsigned un = (unsigned)idx / 10u;
    int n = (int)un;
    int f = idx - n * 10;
    int t = n >> 10, p = n & 1023;
    out[((t * F_OUT + f) << 10) + p] = s;
}

// ---------------------------------------------------------------------------
extern "C" void kernel_launch(void* const* d_in, const int* in_sizes, int n_in,
                              void* d_out, int out_size, void* d_ws, size_t ws_size,
                              hipStream_t stream)
{
    const float* in1 = (const float*)d_in[0];
    const float* in2 = (const float*)d_in[1];
    const float* aw  = (const float*)d_in[2];
    const float* w1  = (const float*)d_in[3];
    const float* b1  = (const float*)d_in[4];
    const float* w2  = (const float*)d_in[5];
    const float* b2  = (const float*)d_in[6];
    const float* w3  = (const float*)d_in[7];
    const float* b3  = (const float*)d_in[8];
    float* out = (float*)d_out;

    // chunk config bounded by ws_size; chunk lengths stay multiples of
    // DTILE / MTILE so tile loops are exact.
    int nchunks, mchunks;
    if (ws_size >= (size_t)32 << 20) { nchunks = 128; mchunks = 128; }  // 29.6 MB
    else                             { nchunks = 32;  mchunks = 32;  }  // 7.9 MB
    int nclen = N_TOK / nchunks;   // 40 / 160
    int mclen = N_TOK / mchunks;   // 40 / 160

    float* ws    = (float*)d_ws;
    float* Q     = ws;                        // N*FP
    float* K     = Q + N_TOK * FP;
    float* V     = K + N_TOK * FP;
    float* dpart = V + N_TOK * FP;            // nchunks*N
    float* opart = dpart + nchunks * N_TOK;   // mchunks*N*10

    qkv_kernel<<<600, 256, 0, stream>>>(in1, in2, w1, b1, w2, b2, w3, b3, Q, K, V);
    denom_kernel<<<5 * nchunks, 256, 0, stream>>>(Q, K, dpart, nclen);
    invw_kernel<<<N_TOK / 256, 256, 0, stream>>>(dpart, aw, K, nchunks);
    main_kernel<<<4 * mchunks, 256, 0, stream>>>(Q, K, V, aw, opart, mclen);
    reduce_kernel<<<(N_TOK * F_OUT) / 256, 256, 0, stream>>>(opart, out, mchunks);
}